// Round 2
// baseline (155.359 us; speedup 1.0000x reference)
//
#include <hip/hip_runtime.h>

// Problem constants: B=4, L=2048, C=64, D=4
#define BB 4
#define LL 2048
#define KK 256   // a-chains per batch = C*D; each a-chain has 4 j-subchains sharing A

// Layout notes (all verified against reference flat order):
//  A flat idx   (b,t,c,i)   = (b*L+t)*256 + k          where k = c*4+i
//  X flat idx   (b,t,c,i,j) = ((b*L+t)*256 + k)*4 + j  -> float4 idx = (b*L+t)*256 + k
//  out float2 idx same as X flat idx -> float4 idx = 2*((b*L+t)*256 + k) + {0,1}
// So ONE index `idx = (b*L+t)*256 + k` drives A (scalar), X (float4), out (2x float4).

// ---------------- Phase 1: per-(b,g,k) chunk aggregates ----------------
// p = prod of A over chunk (shared by the 4 j-chains); s_j = chunk scan of X_j.
template<int G, int LOGG>
__global__ __launch_bounds__(256) void pscan_phase1(
    const float* __restrict__ A_re, const float* __restrict__ A_im,
    const float4* __restrict__ X4_re, const float4* __restrict__ X4_im,
    float2* __restrict__ agg_p, float4* __restrict__ agg_s) {
  constexpr int T = LL / G;
  int u  = blockIdx.x * 256 + threadIdx.x;   // [0, BB*G*KK)
  int k  = u & (KK - 1);
  int bg = u >> 8;                           // b*G + g
  int g  = bg & (G - 1);
  int b  = bg >> LOGG;
  int t0 = g * T;
  long base = (long)(b * LL + t0) * KK + k;

  float p_re = 1.f, p_im = 0.f;
  float s_re[4] = {0.f, 0.f, 0.f, 0.f};
  float s_im[4] = {0.f, 0.f, 0.f, 0.f};
#pragma unroll 8
  for (int t = 0; t < T; ++t) {
    long idx = base + (long)t * KK;
    float are = A_re[idx], aim = A_im[idx];
    float4 xr = X4_re[idx], xi = X4_im[idx];
    float xrv[4] = {xr.x, xr.y, xr.z, xr.w};
    float xiv[4] = {xi.x, xi.y, xi.z, xi.w};
#pragma unroll
    for (int j = 0; j < 4; ++j) {
      float nr = fmaf(are, s_re[j], fmaf(-aim, s_im[j], xrv[j]));
      float ni = fmaf(are, s_im[j], fmaf( aim, s_re[j], xiv[j]));
      s_re[j] = nr; s_im[j] = ni;
    }
    float npr = are * p_re - aim * p_im;
    float npi = are * p_im + aim * p_re;
    p_re = npr; p_im = npi;
  }
  agg_p[u]       = make_float2(p_re, p_im);
  agg_s[2*u]     = make_float4(s_re[0], s_im[0], s_re[1], s_im[1]);
  agg_s[2*u + 1] = make_float4(s_re[2], s_im[2], s_re[3], s_im[3]);
}

// ---------------- Phase 2: exclusive scan of aggregates over g ----------------
// One lane per (chain, g); segmented Hillis-Steele over G lanes via shuffles.
// combine(earlier l, current c): p = p_c*p_l ; s_j = p_c*s_l_j + s_c_j
template<int G, int LOGG>
__global__ __launch_bounds__(256) void pscan_phase2(
    const float2* __restrict__ agg_p, float4* __restrict__ agg_s) {
  int u = blockIdx.x * 256 + threadIdx.x;    // [0, BB*KK*G)
  int g = u & (G - 1);
  int chain = u >> LOGG;                     // b*KK + k
  int b = chain >> 8;
  int k = chain & (KK - 1);
  long idx = (long)(b * G + g) * KK + k;     // matches phase-1's u for (b,g,k)

  float2 p  = agg_p[idx];
  float4 s01 = agg_s[2*idx], s23 = agg_s[2*idx + 1];
  float pr = p.x, pi = p.y;
  float sr[4] = {s01.x, s01.z, s23.x, s23.z};
  float si[4] = {s01.y, s01.w, s23.y, s23.w};

#pragma unroll
  for (int d = 1; d < G; d <<= 1) {
    float plr = __shfl_up(pr, d, 64);
    float pli = __shfl_up(pi, d, 64);
    float slr[4], sli[4];
#pragma unroll
    for (int j = 0; j < 4; ++j) {
      slr[j] = __shfl_up(sr[j], d, 64);
      sli[j] = __shfl_up(si[j], d, 64);
    }
    if (g >= d) {
#pragma unroll
      for (int j = 0; j < 4; ++j) {
        float nr = fmaf(pr, slr[j], fmaf(-pi, sli[j], sr[j]));
        float ni = fmaf(pr, sli[j], fmaf( pi, slr[j], si[j]));
        sr[j] = nr; si[j] = ni;
      }
      float npr = pr * plr - pi * pli;
      float npi = pr * pli + pi * plr;
      pr = npr; pi = npi;
    }
  }
  // exclusive = inclusive of (g-1); g==0 -> identity (s=0)
  float er[4], ei[4];
#pragma unroll
  for (int j = 0; j < 4; ++j) {
    er[j] = __shfl_up(sr[j], 1, 64);
    ei[j] = __shfl_up(si[j], 1, 64);
  }
  if (g == 0) {
#pragma unroll
    for (int j = 0; j < 4; ++j) { er[j] = 0.f; ei[j] = 0.f; }
  }
  agg_s[2*idx]     = make_float4(er[0], ei[0], er[1], ei[1]);
  agg_s[2*idx + 1] = make_float4(er[2], ei[2], er[3], ei[3]);
}

// ---------------- Phase 3: seed with carry, re-run recurrence, write out ----------------
template<int G, int LOGG>
__global__ __launch_bounds__(256) void pscan_phase3(
    const float* __restrict__ A_re, const float* __restrict__ A_im,
    const float4* __restrict__ X4_re, const float4* __restrict__ X4_im,
    const float4* __restrict__ agg_s, float4* __restrict__ out4) {
  constexpr int T = LL / G;
  int u  = blockIdx.x * 256 + threadIdx.x;
  int k  = u & (KK - 1);
  int bg = u >> 8;
  int g  = bg & (G - 1);
  int b  = bg >> LOGG;
  int t0 = g * T;
  long base = (long)(b * LL + t0) * KK + k;

  float4 c01 = agg_s[2*u], c23 = agg_s[2*u + 1];
  float yr[4] = {c01.x, c01.z, c23.x, c23.z};
  float yi[4] = {c01.y, c01.w, c23.y, c23.w};
#pragma unroll 8
  for (int t = 0; t < T; ++t) {
    long idx = base + (long)t * KK;
    float are = A_re[idx], aim = A_im[idx];
    float4 xr = X4_re[idx], xi = X4_im[idx];
    float xrv[4] = {xr.x, xr.y, xr.z, xr.w};
    float xiv[4] = {xi.x, xi.y, xi.z, xi.w};
#pragma unroll
    for (int j = 0; j < 4; ++j) {
      float nr = fmaf(are, yr[j], fmaf(-aim, yi[j], xrv[j]));
      float ni = fmaf(are, yi[j], fmaf( aim, yr[j], xiv[j]));
      yr[j] = nr; yi[j] = ni;
    }
    out4[2*idx]     = make_float4(yr[0], yi[0], yr[1], yi[1]);
    out4[2*idx + 1] = make_float4(yr[2], yi[2], yr[3], yi[3]);
  }
}

template<int G, int LOGG>
static void launch_all(const float* A_re, const float* A_im,
                       const float4* X4_re, const float4* X4_im,
                       void* d_ws, float4* out4, hipStream_t stream) {
  float2* agg_p = (float2*)d_ws;
  float4* agg_s = (float4*)((char*)d_ws + (size_t)BB * G * KK * sizeof(float2));
  int blocks = BB * G;   // (BB*G*KK)/256, KK=256
  pscan_phase1<G, LOGG><<<blocks, 256, 0, stream>>>(A_re, A_im, X4_re, X4_im, agg_p, agg_s);
  pscan_phase2<G, LOGG><<<blocks, 256, 0, stream>>>(agg_p, agg_s);
  pscan_phase3<G, LOGG><<<blocks, 256, 0, stream>>>(A_re, A_im, X4_re, X4_im, agg_s, out4);
}

extern "C" void kernel_launch(void* const* d_in, const int* in_sizes, int n_in,
                              void* d_out, int out_size, void* d_ws, size_t ws_size,
                              hipStream_t stream) {
  const float*  A_re  = (const float*)d_in[0];
  const float*  A_im  = (const float*)d_in[1];
  const float4* X4_re = (const float4*)d_in[2];
  const float4* X4_im = (const float4*)d_in[3];
  float4* out4 = (float4*)d_out;

  const size_t need64 = (size_t)BB * 64 * KK * (sizeof(float2) + 2 * sizeof(float4)); // 2.62 MB
  if (ws_size >= need64) {
    launch_all<64, 6>(A_re, A_im, X4_re, X4_im, d_ws, out4, stream);
  } else {
    launch_all<32, 5>(A_re, A_im, X4_re, X4_im, d_ws, out4, stream);  // 1.31 MB
  }
}